// Round 10
// baseline (282.600 us; speedup 1.0000x reference)
//
#include <hip/hip_runtime.h>

// asymmetricLoss: out = mean(w * |x - y|), w = 0.7 if x<y else 0.3
// x,y: fp32, shape (32,1,1024,1024) -> N = 33,554,432 elements.
//
// R6 post-mortem: compiler re-serialized loads (VGPR=28, 2 loads in flight,
// ~106us regardless of L3 residency) -> outstanding-request-depth bound.
// R7 fix: explicit batch-of-8 float4-pair loads + sched_barrier(0) fence so
// all 16 dwordx4 issue before any compute consumes them.

#define N_TOTAL 33554432
#define N4      (N_TOTAL / 4)     // 8,388,608 float4 pairs
#define NBLOCKS 2048
#define NTHREADS 256
#define STRIDE  (NBLOCKS * NTHREADS)          // 524,288 threads
#define PER_THREAD (N4 / STRIDE)              // 16 float4-pairs per thread
#define BATCH 8
#define NBATCH (PER_THREAD / BATCH)           // 2

__global__ __launch_bounds__(NTHREADS) void
asym_partial_kernel(const float4* __restrict__ x,
                    const float4* __restrict__ y,
                    float* __restrict__ partials) {
    const int tid = blockIdx.x * NTHREADS + threadIdx.x;

    float acc0 = 0.0f, acc1 = 0.0f, acc2 = 0.0f, acc3 = 0.0f;

    #pragma unroll
    for (int ib = 0; ib < NBATCH; ++ib) {
        float4 xv[BATCH], yv[BATCH];
        // Phase 1: issue all 16 global_load_dwordx4 back-to-back.
        #pragma unroll
        for (int j = 0; j < BATCH; ++j) {
            const int i = tid + (ib * BATCH + j) * STRIDE;
            xv[j] = x[i];
            yv[j] = y[i];
        }
        // Fence: nothing may be scheduled across -> loads stay batched.
        __builtin_amdgcn_sched_barrier(0);
        // Phase 2: consume (compiler emits progressive s_waitcnt vmcnt(N)).
        #pragma unroll
        for (int j = 0; j < BATCH; ++j) {
            float d0 = xv[j].x - yv[j].x;
            float d1 = xv[j].y - yv[j].y;
            float d2 = xv[j].z - yv[j].z;
            float d3 = xv[j].w - yv[j].w;
            // w*|d| with w = 0.7 if d<0 else 0.3  ==  max(0.3*d, -0.7*d)
            acc0 += fmaxf(0.3f * d0, -0.7f * d0);
            acc1 += fmaxf(0.3f * d1, -0.7f * d1);
            acc2 += fmaxf(0.3f * d2, -0.7f * d2);
            acc3 += fmaxf(0.3f * d3, -0.7f * d3);
        }
    }
    float acc = (acc0 + acc1) + (acc2 + acc3);

    // wave (64-lane) shuffle reduce
    #pragma unroll
    for (int off = 32; off > 0; off >>= 1)
        acc += __shfl_down(acc, off, 64);
    __shared__ float lds[NTHREADS / 64];
    int lane = threadIdx.x & 63;
    int wave = threadIdx.x >> 6;
    if (lane == 0) lds[wave] = acc;
    __syncthreads();
    if (threadIdx.x == 0) {
        float s = 0.0f;
        #pragma unroll
        for (int w = 0; w < NTHREADS / 64; ++w) s += lds[w];
        partials[blockIdx.x] = s;
    }
}

__global__ __launch_bounds__(NTHREADS) void
asym_final_kernel(const float* __restrict__ partials,
                  float* __restrict__ out) {
    float acc = 0.0f;
    for (int i = threadIdx.x; i < NBLOCKS; i += NTHREADS) acc += partials[i];
    #pragma unroll
    for (int off = 32; off > 0; off >>= 1)
        acc += __shfl_down(acc, off, 64);
    __shared__ float lds[NTHREADS / 64];
    int lane = threadIdx.x & 63;
    int wave = threadIdx.x >> 6;
    if (lane == 0) lds[wave] = acc;
    __syncthreads();
    if (threadIdx.x == 0) {
        float s = 0.0f;
        #pragma unroll
        for (int w = 0; w < NTHREADS / 64; ++w) s += lds[w];
        out[0] = s * (1.0f / (float)N_TOTAL);
    }
}

extern "C" void kernel_launch(void* const* d_in, const int* in_sizes, int n_in,
                              void* d_out, int out_size, void* d_ws, size_t ws_size,
                              hipStream_t stream) {
    const float4* x = (const float4*)d_in[0];
    const float4* y = (const float4*)d_in[1];
    float* partials = (float*)d_ws;   // NBLOCKS floats = 8 KB
    float* out = (float*)d_out;

    asym_partial_kernel<<<NBLOCKS, NTHREADS, 0, stream>>>(x, y, partials);
    asym_final_kernel<<<1, NTHREADS, 0, stream>>>(partials, out);
}

// Round 13
// 278.699 us; speedup vs baseline: 1.0140x; 1.0140x over previous
//
#include <hip/hip_runtime.h>

// asymmetricLoss: out = mean(w * |x - y|), w = 0.7 if x<y else 0.3
// x,y: fp32, N = 33,554,432 elements (256 MiB total read).
//
// R10 post-mortem: three codegens (VGPR 12/28/36) all land at ~106us,
// 2.53 TB/s effective, no saturated component -> ablate, don't theorize.
// R11/R13: 4-way within-probe A/B. Four disjoint quarters, four configs:
//   qA: 8192 blocks, 1 pair/thread (max waves, no loop)
//   qB: nontemporal loads (L1 bypass) — via native ext_vector_type
//   qC: control = R5 grid-stride structure
//   qD: wave-contiguous walk (sequential DRAM pages per wave)
// Each is a separate dispatch -> separate rocprof row. Sum is exact.

#define N_TOTAL 33554432
#define N4      (N_TOTAL / 4)     // 8,388,608 float4 pairs
#define QP      (N4 / 4)          // 2,097,152 pairs per quarter
#define GS      (2048 * 256)      // grid-stride thread count for qB/qC/qD

typedef float f32x4 __attribute__((ext_vector_type(4)));

__device__ __forceinline__ float elem4(const float4 xv, const float4 yv) {
    float d0 = xv.x - yv.x;
    float d1 = xv.y - yv.y;
    float d2 = xv.z - yv.z;
    float d3 = xv.w - yv.w;
    // w*|d| with w = 0.7 if d<0 else 0.3  ==  max(0.3*d, -0.7*d)
    return fmaxf(0.3f * d0, -0.7f * d0) + fmaxf(0.3f * d1, -0.7f * d1)
         + fmaxf(0.3f * d2, -0.7f * d2) + fmaxf(0.3f * d3, -0.7f * d3);
}

__device__ __forceinline__ float elem4v(const f32x4 xv, const f32x4 yv) {
    float d0 = xv.x - yv.x;
    float d1 = xv.y - yv.y;
    float d2 = xv.z - yv.z;
    float d3 = xv.w - yv.w;
    return fmaxf(0.3f * d0, -0.7f * d0) + fmaxf(0.3f * d1, -0.7f * d1)
         + fmaxf(0.3f * d2, -0.7f * d2) + fmaxf(0.3f * d3, -0.7f * d3);
}

__device__ __forceinline__ void block_reduce_store(float acc, float* __restrict__ dst) {
    #pragma unroll
    for (int off = 32; off > 0; off >>= 1)
        acc += __shfl_down(acc, off, 64);
    __shared__ float lds[4];
    int lane = threadIdx.x & 63;
    int wave = threadIdx.x >> 6;
    if (lane == 0) lds[wave] = acc;
    __syncthreads();
    if (threadIdx.x == 0) {
        float s = 0.0f;
        #pragma unroll
        for (int w = 0; w < 4; ++w) s += lds[w];
        dst[blockIdx.x] = s;
    }
}

// qA: quarter 0, 8192 blocks x 256 thr, exactly 1 float4-pair per thread.
__global__ __launch_bounds__(256) void
asym_qA(const float4* __restrict__ x, const float4* __restrict__ y,
        float* __restrict__ p) {
    int i = blockIdx.x * 256 + threadIdx.x;        // [0, QP)
    block_reduce_store(elem4(x[i], y[i]), p);
}

// qB: quarter 1, grid-stride, nontemporal (L1-bypass) loads.
__global__ __launch_bounds__(256) void
asym_qB(const float4* __restrict__ x, const float4* __restrict__ y,
        float* __restrict__ p) {
    const f32x4* xv4 = (const f32x4*)x;
    const f32x4* yv4 = (const f32x4*)y;
    int tid = blockIdx.x * 256 + threadIdx.x;
    float acc = 0.0f;
    #pragma unroll
    for (int k = 0; k < 4; ++k) {
        int i = QP + tid + k * GS;
        f32x4 xv = __builtin_nontemporal_load(&xv4[i]);
        f32x4 yv = __builtin_nontemporal_load(&yv4[i]);
        acc += elem4v(xv, yv);
    }
    block_reduce_store(acc, p);
}

// qC: quarter 2, control — plain grid-stride (R5 structure, scaled to 1/4).
__global__ __launch_bounds__(256) void
asym_qC(const float4* __restrict__ x, const float4* __restrict__ y,
        float* __restrict__ p) {
    int tid = blockIdx.x * 256 + threadIdx.x;
    float acc = 0.0f;
    #pragma unroll
    for (int k = 0; k < 4; ++k) {
        int i = 2 * QP + tid + k * GS;
        acc += elem4(x[i], y[i]);
    }
    block_reduce_store(acc, p);
}

// qD: quarter 3, wave-contiguous: each wave walks 4 sequential 1KB segments.
__global__ __launch_bounds__(256) void
asym_qD(const float4* __restrict__ x, const float4* __restrict__ y,
        float* __restrict__ p) {
    int gw   = (blockIdx.x * 256 + threadIdx.x) >> 6;   // global wave id
    int lane = threadIdx.x & 63;
    float acc = 0.0f;
    #pragma unroll
    for (int it = 0; it < 4; ++it) {
        int i = 3 * QP + gw * 256 + it * 64 + lane;
        acc += elem4(x[i], y[i]);
    }
    block_reduce_store(acc, p);
}

// final: reduce 8192 + 3*2048 = 14336 partials, scale, write scalar.
__global__ __launch_bounds__(256) void
asym_final(const float* __restrict__ partials, float* __restrict__ out) {
    float acc = 0.0f;
    for (int i = threadIdx.x; i < 14336; i += 256) acc += partials[i];
    #pragma unroll
    for (int off = 32; off > 0; off >>= 1)
        acc += __shfl_down(acc, off, 64);
    __shared__ float lds[4];
    int lane = threadIdx.x & 63;
    int wave = threadIdx.x >> 6;
    if (lane == 0) lds[wave] = acc;
    __syncthreads();
    if (threadIdx.x == 0) {
        float s = 0.0f;
        #pragma unroll
        for (int w = 0; w < 4; ++w) s += lds[w];
        out[0] = s * (1.0f / (float)N_TOTAL);
    }
}

extern "C" void kernel_launch(void* const* d_in, const int* in_sizes, int n_in,
                              void* d_out, int out_size, void* d_ws, size_t ws_size,
                              hipStream_t stream) {
    const float4* x = (const float4*)d_in[0];
    const float4* y = (const float4*)d_in[1];
    float* ws = (float*)d_ws;
    float* pA = ws;              // 8192 partials
    float* pB = ws + 8192;       // 2048
    float* pC = ws + 10240;      // 2048
    float* pD = ws + 12288;      // 2048  (total 56 KB of d_ws)
    float* out = (float*)d_out;

    asym_qA<<<8192, 256, 0, stream>>>(x, y, pA);
    asym_qB<<<2048, 256, 0, stream>>>(x, y, pB);
    asym_qC<<<2048, 256, 0, stream>>>(x, y, pC);
    asym_qD<<<2048, 256, 0, stream>>>(x, y, pD);
    asym_final<<<1, 256, 0, stream>>>(ws, out);
}